// Round 1
// baseline (706.328 us; speedup 1.0000x reference)
//
#include <hip/hip_runtime.h>
#include <hip/hip_bf16.h>
#include <math.h>

// Problem constants (from reference: BSZ, L, D, K = 4, 4096, 512, 4)
#define BSZ   4
#define LSEQ  4096
#define DDIM  512
#define KBAND 4
#define MROWS (BSZ*LSEQ)          // 16384
#define BLD   (MROWS*DDIM)        // 8388608
#define CHUNK 64
#define NCH   (LSEQ/CHUNK)        // 64

// ---------------------------------------------------------------------------
// Kernel 1: tables — a^k = exp(lam*dta*k) for k=0..CHUNK, and band inverse maps
// ---------------------------------------------------------------------------
__global__ void k_prep(const float* __restrict__ omega,
                       const float* __restrict__ log_gamma,
                       const float* __restrict__ dt,
                       const int*   __restrict__ band_idx,
                       float* __restrict__ apR, float* __restrict__ apI,
                       int* __restrict__ bandOf, int* __restrict__ posOf)
{
    int gid = blockIdx.x * blockDim.x + threadIdx.x;
    float dta = fabsf(dt[0]);
    if (gid < (CHUNK+1)*DDIM) {
        int k = gid / DDIM, d = gid % DDIM;
        float g = -expf(log_gamma[d]);      // lam.re
        float w = omega[d];                 // lam.im
        float e = expf(g * dta * (float)k);
        float s, c;
        sincosf(w * dta * (float)k, &s, &c);
        apR[gid] = e * c;
        apI[gid] = e * s;
    }
    if (gid < DDIM) {
        int d = band_idx[gid];              // gid = k*128 + j
        bandOf[d] = gid >> 7;
        posOf[d]  = gid & 127;
    }
}

// ---------------------------------------------------------------------------
// Kernel 2: gate[b,l] = sigmoid(x.W_gate + b_gate) * (1 + tanh(sg)*mean|x-z|)
// one wave per row
// ---------------------------------------------------------------------------
__global__ void k_gate(const float* __restrict__ x,
                       const float* __restrict__ z_prev,
                       const float* __restrict__ Wg,
                       const float* __restrict__ bg,
                       const float* __restrict__ sg,
                       float* __restrict__ gate)
{
    int row  = blockIdx.x * 4 + (threadIdx.x >> 6);
    int lane = threadIdx.x & 63;
    const float4* xr = (const float4*)(x      + (size_t)row * DDIM);
    const float4* zr = (const float4*)(z_prev + (size_t)row * DDIM);
    const float4* wg = (const float4*)Wg;
    float dot = 0.f, sur = 0.f;
#pragma unroll
    for (int i = 0; i < 2; i++) {
        float4 a = xr[lane + i*64];
        float4 z = zr[lane + i*64];
        float4 w = wg[lane + i*64];
        dot += a.x*w.x + a.y*w.y + a.z*w.z + a.w*w.w;
        sur += fabsf(a.x-z.x) + fabsf(a.y-z.y) + fabsf(a.z-z.z) + fabsf(a.w-z.w);
    }
#pragma unroll
    for (int m = 32; m; m >>= 1) { dot += __shfl_xor(dot, m); sur += __shfl_xor(sur, m); }
    if (lane == 0) {
        float g = 1.f / (1.f + expf(-(dot + bg[0])));
        g *= (1.f + tanhf(sg[0]) * (sur * (1.f/512.f)));
        gate[row] = g;
    }
}

// ---------------------------------------------------------------------------
// Kernel 3: fp32 GEMM  C[m][n] = sum_k x[m][k]*W[n][k] + bias[n]
// W = [W_psi(1024 rows); W_phi(1024 rows)], outputs to 4 planes of (M,512):
// plane0=psi_re, 1=psi_im, 2=phi_re, 3=phi_im
// BM=128, BN=64, BK=32, 256 threads, 8x4 per thread
// ---------------------------------------------------------------------------
__launch_bounds__(256)
__global__ void k_gemm(const float* __restrict__ x,
                       const float* __restrict__ Wpsi, const float* __restrict__ bpsi,
                       const float* __restrict__ Wphi, const float* __restrict__ bphi,
                       float* __restrict__ psiR, float* __restrict__ psiI,
                       float* __restrict__ phiR, float* __restrict__ phiI)
{
    __shared__ float As[32][128+4];
    __shared__ float Bs[32][64+4];

    int bm = blockIdx.x & 127;     // M-fast: consecutive blocks reuse the W tile
    int bn = blockIdx.x >> 7;
    int m0 = bm * 128, n0 = bn * 64;
    const float* Wbase = (n0 < 1024) ? (Wpsi + (size_t)n0 * 512)
                                     : (Wphi + (size_t)(n0 - 1024) * 512);
    int tid = threadIdx.x;
    float acc[8][4];
#pragma unroll
    for (int r = 0; r < 8; r++)
#pragma unroll
        for (int c = 0; c < 4; c++) acc[r][c] = 0.f;

    int tm = (tid >> 4) * 8;
    int tn = (tid & 15) * 4;

    for (int k0 = 0; k0 < 512; k0 += 32) {
        // A tile: 128x32 floats = 1024 float4; 4 per thread
#pragma unroll
        for (int i = 0; i < 4; i++) {
            int f = tid + i*256;
            int row = f >> 3, kq = (f & 7) * 4;
            float4 v = *(const float4*)(x + (size_t)(m0 + row)*512 + k0 + kq);
            As[kq+0][row] = v.x; As[kq+1][row] = v.y;
            As[kq+2][row] = v.z; As[kq+3][row] = v.w;
        }
        // B tile: 64x32 floats = 512 float4; 2 per thread
#pragma unroll
        for (int i = 0; i < 2; i++) {
            int f = tid + i*256;
            int row = f >> 3, kq = (f & 7) * 4;
            float4 v = *(const float4*)(Wbase + (size_t)row*512 + k0 + kq);
            Bs[kq+0][row] = v.x; Bs[kq+1][row] = v.y;
            Bs[kq+2][row] = v.z; Bs[kq+3][row] = v.w;
        }
        __syncthreads();
#pragma unroll
        for (int kk = 0; kk < 32; kk++) {
            float a[8], bq[4];
            *(float4*)&a[0] = *(const float4*)&As[kk][tm];
            *(float4*)&a[4] = *(const float4*)&As[kk][tm+4];
            *(float4*)&bq[0] = *(const float4*)&Bs[kk][tn];
#pragma unroll
            for (int r = 0; r < 8; r++)
#pragma unroll
                for (int c = 0; c < 4; c++)
                    acc[r][c] += a[r] * bq[c];
        }
        __syncthreads();
    }
    // epilogue
    const float* bias = (n0 < 1024) ? (bpsi + n0) : (bphi + (n0 - 1024));
    float4 bb = *(const float4*)(bias + tn);
    int p = n0 >> 9;
    float* outp = (p == 0) ? psiR : (p == 1) ? psiI : (p == 2) ? phiR : phiI;
    int col = (n0 & 511) + tn;
#pragma unroll
    for (int r = 0; r < 8; r++) {
        float4 o;
        o.x = acc[r][0] + bb.x; o.y = acc[r][1] + bb.y;
        o.z = acc[r][2] + bb.z; o.w = acc[r][3] + bb.w;
        *(float4*)(outp + (size_t)(m0 + tm + r)*512 + col) = o;
    }
}

// ---------------------------------------------------------------------------
// Kernel 4: chunked local scan, in place over psi planes:
//   U = gate*B_vec*psi ;  H_t = a*H_{t-1} + U_t  (H_{-1}=0 per chunk)
// block = (b, chunk), 512 threads (one per d)
// ---------------------------------------------------------------------------
__launch_bounds__(512)
__global__ void k_scan(float* __restrict__ HR, float* __restrict__ HI,
                       const float* __restrict__ gate,
                       const float* __restrict__ Bvec,
                       const float* __restrict__ apR, const float* __restrict__ apI,
                       float* __restrict__ carR, float* __restrict__ carI)
{
    int b = blockIdx.x >> 6;       // NCH = 64
    int c = blockIdx.x & 63;
    int d = threadIdx.x;
    float ar = apR[DDIM + d], ai = apI[DDIM + d];   // a^1
    float bv = Bvec[d];
    float hr = 0.f, hi = 0.f;
    int t0 = c * CHUNK;
    size_t base = ((size_t)b * LSEQ + t0) * DDIM + d;
    const float* grow = gate + (size_t)b * LSEQ + t0;
#pragma unroll 4
    for (int t = 0; t < CHUNK; t++) {
        float pr = HR[base], pi = HI[base];
        float g  = grow[t] * bv;
        float ur = g * pr, ui = g * pi;
        float nr = ar*hr - ai*hi + ur;
        float ni = ar*hi + ai*hr + ui;
        hr = nr; hi = ni;
        HR[base] = hr; HI[base] = hi;
        base += DDIM;
    }
    size_t ci = ((size_t)(b * NCH + c)) * DDIM + d;
    carR[ci] = hr; carI[ci] = hi;
}

// ---------------------------------------------------------------------------
// Kernel 5: sequential carry combine per channel (in place -> inclusive carry)
// ---------------------------------------------------------------------------
__global__ void k_carry(float* __restrict__ carR, float* __restrict__ carI,
                        const float* __restrict__ apR, const float* __restrict__ apI)
{
    int gid = blockIdx.x * blockDim.x + threadIdx.x;   // 0..2047
    int b = gid >> 9, d = gid & 511;
    float dr = apR[CHUNK*DDIM + d], di = apI[CHUNK*DDIM + d];  // a^CHUNK
    size_t i0 = ((size_t)(b * NCH)) * DDIM + d;
    float cr = carR[i0], ci = carI[i0];
    for (int c = 1; c < NCH; c++) {
        size_t idx = i0 + (size_t)c * DDIM;
        float xr = carR[idx], xi = carI[idx];
        float nr = dr*cr - di*ci + xr;
        float ni = dr*ci + di*cr + xi;
        cr = nr; ci = ni;
        carR[idx] = cr; carI[idx] = ci;
    }
}

// ---------------------------------------------------------------------------
// Kernel 6: carry fixup + exact projection + band mixing + output
// block per (b,t), 512 threads
// ---------------------------------------------------------------------------
__device__ __forceinline__ float2 blockSum2(float a, float b, float* red)
{
#pragma unroll
    for (int m = 32; m; m >>= 1) { a += __shfl_xor(a, m); b += __shfl_xor(b, m); }
    int tid = threadIdx.x, w = tid >> 6;
    if ((tid & 63) == 0) { red[w*2] = a; red[w*2+1] = b; }
    __syncthreads();
    a = 0.f; b = 0.f;
#pragma unroll
    for (int i = 0; i < 8; i++) { a += red[i*2]; b += red[i*2+1]; }
    __syncthreads();
    return make_float2(a, b);
}

__launch_bounds__(512)
__global__ void k_out(const float* __restrict__ HR, const float* __restrict__ HI,
                      const float* __restrict__ phR, const float* __restrict__ phI,
                      const float* __restrict__ carR, const float* __restrict__ carI,
                      const float* __restrict__ apR, const float* __restrict__ apI,
                      const int* __restrict__ bandOf, const int* __restrict__ posOf,
                      const float* __restrict__ tau, const float* __restrict__ beta,
                      float* __restrict__ out)
{
    __shared__ float sA[512], sB[512], sC[512];
    __shared__ float pA[8], pB[8], pC[8];
    __shared__ float red[16];

    int bt = blockIdx.x;
    int b = bt >> 12, t = bt & 4095;
    int d = threadIdx.x;
    size_t idx = (size_t)bt * DDIM + d;

    float hr = HR[idx], hi = HI[idx];
    int c = t >> 6, off = t & 63;
    if (c > 0) {
        size_t ci = ((size_t)(b * NCH + (c - 1))) * DDIM + d;
        float cr = carR[ci], cm = carI[ci];
        float pr = apR[(off + 1) * DDIM + d], pi = apI[(off + 1) * DDIM + d];
        hr += pr*cr - pi*cm;
        hi += pr*cm + pi*cr;
    }
    // exact projection: (z - mean) / (sqrt(var) + 1e-6), real & imag separately
    float2 s = blockSum2(hr, hi, red);
    float mr = s.x * (1.f/512.f), mi = s.y * (1.f/512.f);
    float dr = hr - mr, di = hi - mi;
    float2 v = blockSum2(dr*dr, di*di, red);
    float Hpr = dr / (sqrtf(v.x * (1.f/512.f)) + 1e-6f);
    float Hpi = di / (sqrtf(v.y * (1.f/512.f)) + 1e-6f);

    float pr_ = phR[idx], pi_ = phI[idx];
    float ar_ = Hpr*pr_ + Hpi*pi_;     // conj(H)*phi  (real)
    float ai_ = Hpr*pi_ - Hpi*pr_;     // conj(H)*phi  (imag)
    float dn_ = Hpr*Hpr + Hpi*Hpi;

    int kb = bandOf[d], jb = posOf[d];
    sA[kb*128 + jb] = ar_;
    sB[kb*128 + jb] = ai_;
    sC[kb*128 + jb] = dn_;
    __syncthreads();

    float v0 = sA[d], v1 = sB[d], v2 = sC[d];
#pragma unroll
    for (int m = 32; m; m >>= 1) {
        v0 += __shfl_xor(v0, m); v1 += __shfl_xor(v1, m); v2 += __shfl_xor(v2, m);
    }
    int w = d >> 6;
    if ((d & 63) == 0) { pA[w] = v0; pB[w] = v1; pC[w] = v2; }
    __syncthreads();

    // per-band alpha / density, softmax over K=4 (computed redundantly)
    float tv = tau[0]; tv = (tv < 1e-4f) ? 1e-4f : tv;
    float bt_s = beta[0];
    float aRk[4], aIk[4], dnk[4], mag[4];
    float mx = -1e30f;
#pragma unroll
    for (int k = 0; k < 4; k++) {
        aRk[k] = (pA[2*k] + pA[2*k+1]) * (1.f/128.f);
        aIk[k] = (pB[2*k] + pB[2*k+1]) * (1.f/128.f);
        dnk[k] = (pC[2*k] + pC[2*k+1]) * (1.f/128.f);
        mag[k] = sqrtf(aRk[k]*aRk[k] + aIk[k]*aIk[k]) / tv;
        mx = fmaxf(mx, mag[k]);
    }
    float se = 0.f, ek[4];
#pragma unroll
    for (int k = 0; k < 4; k++) { ek[k] = expf(mag[k] - mx); se += ek[k]; }
    float inv = 1.f / se;

    int kd = kb;
    float ck  = ek[kd] * inv;
    float afR = aRk[kd] * ck * 4.f + bt_s * dnk[kd];
    float afI = aIk[kd] * ck * 4.f;
    out[idx] = Hpr * afR - Hpi * afI;
}

// ---------------------------------------------------------------------------
extern "C" void kernel_launch(void* const* d_in, const int* in_sizes, int n_in,
                              void* d_out, int out_size, void* d_ws, size_t ws_size,
                              hipStream_t stream)
{
    const float* x        = (const float*)d_in[0];
    const float* z_prev   = (const float*)d_in[1];
    const float* W_psi    = (const float*)d_in[2];
    const float* b_psi    = (const float*)d_in[3];
    const float* W_phi    = (const float*)d_in[4];
    const float* b_phi    = (const float*)d_in[5];
    const float* W_gate   = (const float*)d_in[6];
    const float* b_gate   = (const float*)d_in[7];
    const float* omega    = (const float*)d_in[8];
    const float* log_gam  = (const float*)d_in[9];
    const float* dt       = (const float*)d_in[10];
    const float* sg       = (const float*)d_in[11];
    const float* tau      = (const float*)d_in[12];
    const float* beta     = (const float*)d_in[13];
    const float* B_vec    = (const float*)d_in[14];
    const int*   band_idx = (const int*)d_in[15];
    float* out = (float*)d_out;
    float* ws  = (float*)d_ws;

    // workspace layout (floats)
    float* psiR = ws;                    // BLD  -> becomes H_re after scan
    float* psiI = psiR + BLD;            // BLD  -> becomes H_im
    float* phiR = psiI + BLD;            // BLD
    float* phiI = phiR + BLD;            // BLD
    float* gate = phiI + BLD;            // MROWS
    float* apR  = gate + MROWS;          // (CHUNK+1)*DDIM
    float* apI  = apR + (CHUNK+1)*DDIM;
    float* carR = apI + (CHUNK+1)*DDIM;  // BSZ*NCH*DDIM
    float* carI = carR + BSZ*NCH*DDIM;
    int* bandOf = (int*)(carI + BSZ*NCH*DDIM);  // DDIM
    int* posOf  = bandOf + DDIM;                // DDIM

    k_prep<<<((CHUNK+1)*DDIM + 255)/256, 256, 0, stream>>>(
        omega, log_gam, dt, band_idx, apR, apI, bandOf, posOf);

    k_gate<<<MROWS/4, 256, 0, stream>>>(x, z_prev, W_gate, b_gate, sg, gate);

    k_gemm<<<(MROWS/128) * (2048/64), 256, 0, stream>>>(
        x, W_psi, b_psi, W_phi, b_phi, psiR, psiI, phiR, phiI);

    k_scan<<<BSZ * NCH, 512, 0, stream>>>(psiR, psiI, gate, B_vec, apR, apI, carR, carI);

    k_carry<<<(BSZ*DDIM)/256, 256, 0, stream>>>(carR, carI, apR, apI);

    k_out<<<MROWS, 512, 0, stream>>>(psiR, psiI, phiR, phiI, carR, carI,
                                     apR, apI, bandOf, posOf, tau, beta, out);
}

// Round 2
// 413.802 us; speedup vs baseline: 1.7069x; 1.7069x over previous
//
#include <hip/hip_runtime.h>
#include <hip/hip_bf16.h>
#include <math.h>

// Problem constants (from reference: BSZ, L, D, K = 4, 4096, 512, 4)
#define BSZ   4
#define LSEQ  4096
#define DDIM  512
#define KBAND 4
#define MROWS (BSZ*LSEQ)          // 16384
#define BLD   (MROWS*DDIM)        // 8388608
#define CHUNK 64
#define NCH   (LSEQ/CHUNK)        // 64
#define NCOLS 2048                // 2*(2*D) GEMM output columns

typedef __attribute__((ext_vector_type(8))) short  short8;
typedef __attribute__((ext_vector_type(8))) unsigned short u16x8;
typedef __attribute__((ext_vector_type(4))) float  f32x4;

__device__ __forceinline__ unsigned short f2bf(float f) {
    unsigned int u = __float_as_uint(f);
    u = (u + 0x7FFFu + ((u >> 16) & 1u)) >> 16;
    return (unsigned short)u;
}
__device__ __forceinline__ float bf2f(unsigned short h) {
    return __uint_as_float(((unsigned int)h) << 16);
}

__device__ __forceinline__ void gld_lds16(const void* g, void* l) {
    __builtin_amdgcn_global_load_lds(
        (const __attribute__((address_space(1))) void*)g,
        (__attribute__((address_space(3))) void*)l, 16, 0, 0);
}

// ---------------------------------------------------------------------------
// Kernel 1: tables — a^k = exp(lam*dta*k) for k=0..CHUNK, and band inverse maps
// ---------------------------------------------------------------------------
__global__ void k_prep(const float* __restrict__ omega,
                       const float* __restrict__ log_gamma,
                       const float* __restrict__ dt,
                       const int*   __restrict__ band_idx,
                       float* __restrict__ apR, float* __restrict__ apI,
                       int* __restrict__ bandOf, int* __restrict__ posOf)
{
    int gid = blockIdx.x * blockDim.x + threadIdx.x;
    float dta = fabsf(dt[0]);
    if (gid < (CHUNK+1)*DDIM) {
        int k = gid / DDIM, d = gid % DDIM;
        float g = -expf(log_gamma[d]);      // lam.re
        float w = omega[d];                 // lam.im
        float e = expf(g * dta * (float)k);
        float s, c;
        sincosf(w * dta * (float)k, &s, &c);
        apR[gid] = e * c;
        apI[gid] = e * s;
    }
    if (gid < DDIM) {
        int d = band_idx[gid];              // gid = k*128 + j
        bandOf[d] = gid >> 7;
        posOf[d]  = gid & 127;
    }
}

// ---------------------------------------------------------------------------
// Kernel 2: gate[b,l] = sigmoid(x.W_gate + b_gate) * (1 + tanh(sg)*mean|x-z|)
// ---------------------------------------------------------------------------
__global__ void k_gate(const float* __restrict__ x,
                       const float* __restrict__ z_prev,
                       const float* __restrict__ Wg,
                       const float* __restrict__ bg,
                       const float* __restrict__ sg,
                       float* __restrict__ gate)
{
    int row  = blockIdx.x * 4 + (threadIdx.x >> 6);
    int lane = threadIdx.x & 63;
    const float4* xr = (const float4*)(x      + (size_t)row * DDIM);
    const float4* zr = (const float4*)(z_prev + (size_t)row * DDIM);
    const float4* wg = (const float4*)Wg;
    float dot = 0.f, sur = 0.f;
#pragma unroll
    for (int i = 0; i < 2; i++) {
        float4 a = xr[lane + i*64];
        float4 z = zr[lane + i*64];
        float4 w = wg[lane + i*64];
        dot += a.x*w.x + a.y*w.y + a.z*w.z + a.w*w.w;
        sur += fabsf(a.x-z.x) + fabsf(a.y-z.y) + fabsf(a.z-z.z) + fabsf(a.w-z.w);
    }
#pragma unroll
    for (int m = 32; m; m >>= 1) { dot += __shfl_xor(dot, m); sur += __shfl_xor(sur, m); }
    if (lane == 0) {
        float g = 1.f / (1.f + expf(-(dot + bg[0])));
        g *= (1.f + tanhf(sg[0]) * (sur * (1.f/512.f)));
        gate[row] = g;
    }
}

// ---------------------------------------------------------------------------
// Kernel 3a: convert x -> bf16 hi/lo planes, PRE-SWIZZLED within each
// 128-byte k-chunk: dest 16B-group g holds source group (g ^ (m&7)).
// Output lives in d_out (dead until final kernel): Ahi[16384][512], Alo same.
// ---------------------------------------------------------------------------
__global__ void k_cvtA(const float* __restrict__ x,
                       unsigned short* __restrict__ Ahi,
                       unsigned short* __restrict__ Alo)
{
    int gid = blockIdx.x * 256 + threadIdx.x;   // MROWS*64 threads
    int m = gid >> 6, grp = gid & 63;
    int chunk = grp >> 3, g = grp & 7;
    int se = chunk*64 + ((g ^ (m & 7)) << 3);   // source element of 8-run
    const float* xp = x + ((size_t)m << 9) + se;
    u16x8 h, l;
#pragma unroll
    for (int j = 0; j < 8; ++j) {
        float f = xp[j];
        unsigned short hb = f2bf(f);
        h[j] = hb;
        l[j] = f2bf(f - bf2f(hb));
    }
    size_t dst = ((size_t)m << 9) + grp*8;
    *(u16x8*)(Ahi + dst) = h;
    *(u16x8*)(Alo + dst) = l;
}

// ---------------------------------------------------------------------------
// Kernel 3b: convert W=[W_psi;W_phi] -> bf16 hi/lo planes, pre-swizzled by n&7
// ---------------------------------------------------------------------------
__global__ void k_cvtB(const float* __restrict__ Wpsi,
                       const float* __restrict__ Wphi,
                       unsigned short* __restrict__ Bhi,
                       unsigned short* __restrict__ Blo)
{
    int gid = blockIdx.x * 256 + threadIdx.x;   // NCOLS*64 threads
    int n = gid >> 6, grp = gid & 63;
    int chunk = grp >> 3, g = grp & 7;
    int se = chunk*64 + ((g ^ (n & 7)) << 3);
    const float* wp = (n < 1024) ? (Wpsi + ((size_t)n << 9) + se)
                                 : (Wphi + ((size_t)(n - 1024) << 9) + se);
    u16x8 h, l;
#pragma unroll
    for (int j = 0; j < 8; ++j) {
        float f = wp[j];
        unsigned short hb = f2bf(f);
        h[j] = hb;
        l[j] = f2bf(f - bf2f(hb));
    }
    size_t dst = ((size_t)n << 9) + grp*8;
    *(u16x8*)(Bhi + dst) = h;
    *(u16x8*)(Blo + dst) = l;
}

// ---------------------------------------------------------------------------
// Kernel 4: bf16 MFMA GEMM, 3-term split precision.
//   C[m][n] = sum over sections s of A_s[m][k]*B_s[n][k],
//   sections: (Ahi,Bhi) steps 0-7, (Alo,Bhi) 8-15, (Ahi,Blo) 16-23  (K=512 each)
// 128x128 tile, BK=64, 4 waves 2x2, mfma 16x16x32, m97-style 2-barrier loop,
// global_load_lds(16B) linear dest + pre-swizzled source + XOR on ds_read (T2),
// XCD-swizzled blockIdx (T1). Epilogue: +bias, scatter to 4 fp32 planes.
// ---------------------------------------------------------------------------
__global__ __launch_bounds__(256)
void k_gemm_bf16(const unsigned short* __restrict__ Ahi,
                 const unsigned short* __restrict__ Alo,
                 const unsigned short* __restrict__ Bhi,
                 const unsigned short* __restrict__ Blo,
                 const float* __restrict__ bpsi, const float* __restrict__ bphi,
                 float* __restrict__ psiR, float* __restrict__ psiI,
                 float* __restrict__ phiR, float* __restrict__ phiI)
{
    __shared__ __align__(16) char As[16384];
    __shared__ __align__(16) char Bs[16384];

    int bid = blockIdx.x;
    int wg  = (bid & 7) * 256 + (bid >> 3);   // XCD swizzle, nwg=2048 (%8==0)
    int m0 = (wg >> 4) * 128;                 // 128 m-tiles
    int n0 = (wg & 15) * 128;                 // 16 n-tiles (n-fast: A-panel L2 reuse)

    int tid  = threadIdx.x;
    int lane = tid & 63;
    int wv   = tid >> 6;
    int wm = wv >> 1, wn = wv & 1;
    int lr = lane & 15, lk = lane >> 4;

    f32x4 acc[4][4];
#pragma unroll
    for (int mi = 0; mi < 4; ++mi)
#pragma unroll
        for (int ni = 0; ni < 4; ++ni) acc[mi][ni] = (f32x4)0.f;

    for (int s = 0; s < 24; ++s) {
        const unsigned short* Asrc = (s >= 8 && s < 16) ? Alo : Ahi;
        const unsigned short* Bsrc = (s < 16) ? Bhi : Blo;
        int kb2 = (s & 7) << 7;               // byte offset of 64-col chunk

        __syncthreads();                      // protect LDS from overwrite
#pragma unroll
        for (int i = 0; i < 4; ++i) {
            int flat = tid + i * 256;
            int r = flat >> 3, g = flat & 7;
            size_t goff = ((size_t)r << 10) + kb2 + g * 16;
            char* ldst = (char*)(void*)( (char*)0 );  (void)ldst;
            gld_lds16((const char*)Asrc + ((size_t)m0 << 10) + goff,
                      As + (wv * 64 + i * 256) * 16);
            gld_lds16((const char*)Bsrc + ((size_t)n0 << 10) + goff,
                      Bs + (wv * 64 + i * 256) * 16);
        }
        __syncthreads();                      // vmcnt(0) drain + barrier

#pragma unroll
        for (int kk = 0; kk < 2; ++kk) {
            int tb = (kk * 64 + lk * 16) ^ ((lr & 7) << 4);
            short8 af[4], bfr[4];
#pragma unroll
            for (int mi = 0; mi < 4; ++mi) {
                int r = wm * 64 + mi * 16 + lr;
                af[mi] = *(const short8*)(As + r * 128 + tb);
            }
#pragma unroll
            for (int ni = 0; ni < 4; ++ni) {
                int r = wn * 64 + ni * 16 + lr;
                bfr[ni] = *(const short8*)(Bs + r * 128 + tb);
            }
#pragma unroll
            for (int mi = 0; mi < 4; ++mi)
#pragma unroll
                for (int ni = 0; ni < 4; ++ni)
                    acc[mi][ni] = __builtin_amdgcn_mfma_f32_16x16x32_bf16(
                        af[mi], bfr[ni], acc[mi][ni], 0, 0, 0);
        }
    }

    // epilogue: bias + scatter to planes (C/D: col=lane&15, row=(lane>>4)*4+reg)
#pragma unroll
    for (int ni = 0; ni < 4; ++ni) {
        int ncol = n0 + wn * 64 + ni * 16 + lr;
        float bias = (ncol < 1024) ? bpsi[ncol] : bphi[ncol - 1024];
        int p = ncol >> 9;
        float* plane = (p == 0) ? psiR : (p == 1) ? psiI : (p == 2) ? phiR : phiI;
        int col = ncol & 511;
#pragma unroll
        for (int mi = 0; mi < 4; ++mi) {
            int mrow = m0 + wm * 64 + mi * 16 + lk * 4;
#pragma unroll
            for (int j = 0; j < 4; ++j)
                plane[(size_t)(mrow + j) * 512 + col] = acc[mi][ni][j] + bias;
        }
    }
}

// ---------------------------------------------------------------------------
// Kernel 5: chunked local scan, in place over psi planes
// ---------------------------------------------------------------------------
__launch_bounds__(512)
__global__ void k_scan(float* __restrict__ HR, float* __restrict__ HI,
                       const float* __restrict__ gate,
                       const float* __restrict__ Bvec,
                       const float* __restrict__ apR, const float* __restrict__ apI,
                       float* __restrict__ carR, float* __restrict__ carI)
{
    int b = blockIdx.x >> 6;       // NCH = 64
    int c = blockIdx.x & 63;
    int d = threadIdx.x;
    float ar = apR[DDIM + d], ai = apI[DDIM + d];   // a^1
    float bv = Bvec[d];
    float hr = 0.f, hi = 0.f;
    int t0 = c * CHUNK;
    size_t base = ((size_t)b * LSEQ + t0) * DDIM + d;
    const float* grow = gate + (size_t)b * LSEQ + t0;
#pragma unroll 4
    for (int t = 0; t < CHUNK; t++) {
        float pr = HR[base], pi = HI[base];
        float g  = grow[t] * bv;
        float ur = g * pr, ui = g * pi;
        float nr = ar*hr - ai*hi + ur;
        float ni = ar*hi + ai*hr + ui;
        hr = nr; hi = ni;
        HR[base] = hr; HI[base] = hi;
        base += DDIM;
    }
    size_t ci = ((size_t)(b * NCH + c)) * DDIM + d;
    carR[ci] = hr; carI[ci] = hi;
}

// ---------------------------------------------------------------------------
// Kernel 6: sequential carry combine per channel
// ---------------------------------------------------------------------------
__global__ void k_carry(float* __restrict__ carR, float* __restrict__ carI,
                        const float* __restrict__ apR, const float* __restrict__ apI)
{
    int gid = blockIdx.x * blockDim.x + threadIdx.x;   // 0..2047
    int b = gid >> 9, d = gid & 511;
    float dr = apR[CHUNK*DDIM + d], di = apI[CHUNK*DDIM + d];  // a^CHUNK
    size_t i0 = ((size_t)(b * NCH)) * DDIM + d;
    float cr = carR[i0], ci = carI[i0];
    for (int c = 1; c < NCH; c++) {
        size_t idx = i0 + (size_t)c * DDIM;
        float xr = carR[idx], xi = carI[idx];
        float nr = dr*cr - di*ci + xr;
        float ni = dr*ci + di*cr + xi;
        cr = nr; ci = ni;
        carR[idx] = cr; carI[idx] = ci;
    }
}

// ---------------------------------------------------------------------------
// Kernel 7: carry fixup + exact projection + band mixing + output
// ---------------------------------------------------------------------------
__device__ __forceinline__ float2 blockSum2(float a, float b, float* red)
{
#pragma unroll
    for (int m = 32; m; m >>= 1) { a += __shfl_xor(a, m); b += __shfl_xor(b, m); }
    int tid = threadIdx.x, w = tid >> 6;
    if ((tid & 63) == 0) { red[w*2] = a; red[w*2+1] = b; }
    __syncthreads();
    a = 0.f; b = 0.f;
#pragma unroll
    for (int i = 0; i < 8; i++) { a += red[i*2]; b += red[i*2+1]; }
    __syncthreads();
    return make_float2(a, b);
}

__launch_bounds__(512)
__global__ void k_out(const float* __restrict__ HR, const float* __restrict__ HI,
                      const float* __restrict__ phR, const float* __restrict__ phI,
                      const float* __restrict__ carR, const float* __restrict__ carI,
                      const float* __restrict__ apR, const float* __restrict__ apI,
                      const int* __restrict__ bandOf, const int* __restrict__ posOf,
                      const float* __restrict__ tau, const float* __restrict__ beta,
                      float* __restrict__ out)
{
    __shared__ float sA[512], sB[512], sC[512];
    __shared__ float pA[8], pB[8], pC[8];
    __shared__ float red[16];

    int bt = blockIdx.x;
    int b = bt >> 12, t = bt & 4095;
    int d = threadIdx.x;
    size_t idx = (size_t)bt * DDIM + d;

    float hr = HR[idx], hi = HI[idx];
    int c = t >> 6, off = t & 63;
    if (c > 0) {
        size_t ci = ((size_t)(b * NCH + (c - 1))) * DDIM + d;
        float cr = carR[ci], cm = carI[ci];
        float pr = apR[(off + 1) * DDIM + d], pi = apI[(off + 1) * DDIM + d];
        hr += pr*cr - pi*cm;
        hi += pr*cm + pi*cr;
    }
    float2 s = blockSum2(hr, hi, red);
    float mr = s.x * (1.f/512.f), mi = s.y * (1.f/512.f);
    float dr = hr - mr, di = hi - mi;
    float2 v = blockSum2(dr*dr, di*di, red);
    float Hpr = dr / (sqrtf(v.x * (1.f/512.f)) + 1e-6f);
    float Hpi = di / (sqrtf(v.y * (1.f/512.f)) + 1e-6f);

    float pr_ = phR[idx], pi_ = phI[idx];
    float ar_ = Hpr*pr_ + Hpi*pi_;     // conj(H)*phi  (real)
    float ai_ = Hpr*pi_ - Hpi*pr_;     // conj(H)*phi  (imag)
    float dn_ = Hpr*Hpr + Hpi*Hpi;

    int kb = bandOf[d], jb = posOf[d];
    sA[kb*128 + jb] = ar_;
    sB[kb*128 + jb] = ai_;
    sC[kb*128 + jb] = dn_;
    __syncthreads();

    float v0 = sA[d], v1 = sB[d], v2 = sC[d];
#pragma unroll
    for (int m = 32; m; m >>= 1) {
        v0 += __shfl_xor(v0, m); v1 += __shfl_xor(v1, m); v2 += __shfl_xor(v2, m);
    }
    int w = d >> 6;
    if ((d & 63) == 0) { pA[w] = v0; pB[w] = v1; pC[w] = v2; }
    __syncthreads();

    float tv = tau[0]; tv = (tv < 1e-4f) ? 1e-4f : tv;
    float bt_s = beta[0];
    float aRk[4], aIk[4], dnk[4], mag[4];
    float mx = -1e30f;
#pragma unroll
    for (int k = 0; k < 4; k++) {
        aRk[k] = (pA[2*k] + pA[2*k+1]) * (1.f/128.f);
        aIk[k] = (pB[2*k] + pB[2*k+1]) * (1.f/128.f);
        dnk[k] = (pC[2*k] + pC[2*k+1]) * (1.f/128.f);
        mag[k] = sqrtf(aRk[k]*aRk[k] + aIk[k]*aIk[k]) / tv;
        mx = fmaxf(mx, mag[k]);
    }
    float se = 0.f, ek[4];
#pragma unroll
    for (int k = 0; k < 4; k++) { ek[k] = expf(mag[k] - mx); se += ek[k]; }
    float inv = 1.f / se;

    int kd = kb;
    float ck  = ek[kd] * inv;
    float afR = aRk[kd] * ck * 4.f + bt_s * dnk[kd];
    float afI = aIk[kd] * ck * 4.f;
    out[idx] = Hpr * afR - Hpi * afI;
}

// ---------------------------------------------------------------------------
extern "C" void kernel_launch(void* const* d_in, const int* in_sizes, int n_in,
                              void* d_out, int out_size, void* d_ws, size_t ws_size,
                              hipStream_t stream)
{
    const float* x        = (const float*)d_in[0];
    const float* z_prev   = (const float*)d_in[1];
    const float* W_psi    = (const float*)d_in[2];
    const float* b_psi    = (const float*)d_in[3];
    const float* W_phi    = (const float*)d_in[4];
    const float* b_phi    = (const float*)d_in[5];
    const float* W_gate   = (const float*)d_in[6];
    const float* b_gate   = (const float*)d_in[7];
    const float* omega    = (const float*)d_in[8];
    const float* log_gam  = (const float*)d_in[9];
    const float* dt       = (const float*)d_in[10];
    const float* sg       = (const float*)d_in[11];
    const float* tau      = (const float*)d_in[12];
    const float* beta     = (const float*)d_in[13];
    const float* B_vec    = (const float*)d_in[14];
    const int*   band_idx = (const int*)d_in[15];
    float* out = (float*)d_out;
    float* ws  = (float*)d_ws;

    // workspace layout (floats)
    float* psiR = ws;                    // BLD  -> becomes H_re after scan
    float* psiI = psiR + BLD;            // BLD  -> becomes H_im
    float* phiR = psiI + BLD;            // BLD
    float* phiI = phiR + BLD;            // BLD
    float* gate = phiI + BLD;            // MROWS
    float* apR  = gate + MROWS;          // (CHUNK+1)*DDIM
    float* apI  = apR + (CHUNK+1)*DDIM;
    float* carR = apI + (CHUNK+1)*DDIM;  // BSZ*NCH*DDIM
    float* carI = carR + BSZ*NCH*DDIM;
    int* bandOf = (int*)(carI + BSZ*NCH*DDIM);  // DDIM
    int* posOf  = bandOf + DDIM;                // DDIM
    unsigned short* Bhi = (unsigned short*)(posOf + DDIM);   // NCOLS*512 bf16
    unsigned short* Blo = Bhi + (size_t)NCOLS*512;           // NCOLS*512 bf16

    // A-operand bf16 planes live in d_out (dead until k_out writes it):
    // Ahi [16384][512] + Alo [16384][512] = exactly out_size*4 bytes
    unsigned short* Ahi = (unsigned short*)d_out;
    unsigned short* Alo = Ahi + (size_t)MROWS*512;

    k_prep<<<((CHUNK+1)*DDIM + 255)/256, 256, 0, stream>>>(
        omega, log_gam, dt, band_idx, apR, apI, bandOf, posOf);

    k_gate<<<MROWS/4, 256, 0, stream>>>(x, z_prev, W_gate, b_gate, sg, gate);

    k_cvtA<<<(MROWS*64)/256, 256, 0, stream>>>(x, Ahi, Alo);
    k_cvtB<<<(NCOLS*64)/256, 256, 0, stream>>>(W_psi, W_phi, Bhi, Blo);

    k_gemm_bf16<<<(MROWS/128) * (NCOLS/128), 256, 0, stream>>>(
        Ahi, Alo, Bhi, Blo, b_psi, b_phi, psiR, psiI, phiR, phiI);

    k_scan<<<BSZ * NCH, 512, 0, stream>>>(psiR, psiI, gate, B_vec, apR, apI, carR, carI);

    k_carry<<<(BSZ*DDIM)/256, 256, 0, stream>>>(carR, carI, apR, apI);

    k_out<<<MROWS, 512, 0, stream>>>(psiR, psiI, phiR, phiI, carR, carI,
                                     apR, apI, bandOf, posOf, tau, beta, out);
}

// Round 5
// 412.510 us; speedup vs baseline: 1.7123x; 1.0031x over previous
//
#include <hip/hip_runtime.h>
#include <hip/hip_bf16.h>
#include <math.h>

// Problem constants (from reference: BSZ, L, D, K = 4, 4096, 512, 4)
#define BSZ   4
#define LSEQ  4096
#define DDIM  512
#define KBAND 4
#define MROWS (BSZ*LSEQ)          // 16384
#define BLD   (MROWS*DDIM)        // 8388608
#define CHUNK 16
#define NCH   (LSEQ/CHUNK)        // 256
#define NGRP  16                  // groups of 16 chunks
#define TBL   ((CHUNK+1)*DDIM)    // 17*512 a^k table entries
#define NCOLS 2048                // 2*(2*D) GEMM output columns

typedef __attribute__((ext_vector_type(8))) short  short8;
typedef __attribute__((ext_vector_type(8))) unsigned short u16x8;
typedef __attribute__((ext_vector_type(4))) unsigned short u16x4;
typedef __attribute__((ext_vector_type(4))) float  f32x4;

__device__ __forceinline__ unsigned short f2bf(float f) {
    unsigned int u = __float_as_uint(f);
    u = (u + 0x7FFFu + ((u >> 16) & 1u)) >> 16;
    return (unsigned short)u;
}
__device__ __forceinline__ float bf2f(unsigned short h) {
    return __uint_as_float(((unsigned int)h) << 16);
}

__device__ __forceinline__ void gld_lds16(const void* g, void* l) {
    __builtin_amdgcn_global_load_lds(
        (const __attribute__((address_space(1))) void*)g,
        (__attribute__((address_space(3))) void*)l, 16, 0, 0);
}

// ---------------------------------------------------------------------------
// Kernel 1: tables — ap[k]=a^k (k=0..16), apg[k]=a^(16k) (k=0..16), band maps
// ---------------------------------------------------------------------------
__global__ void k_prep(const float* __restrict__ omega,
                       const float* __restrict__ log_gamma,
                       const float* __restrict__ dt,
                       const int*   __restrict__ band_idx,
                       float* __restrict__ apR, float* __restrict__ apI,
                       float* __restrict__ apgR, float* __restrict__ apgI,
                       int* __restrict__ bandOf, int* __restrict__ posOf)
{
    int gid = blockIdx.x * blockDim.x + threadIdx.x;
    float dta = fabsf(dt[0]);
    if (gid < TBL) {
        int k = gid / DDIM, d = gid % DDIM;
        float g = -expf(log_gamma[d]);
        float w = omega[d];
        float e = expf(g * dta * (float)k);
        float s, c;
        sincosf(w * dta * (float)k, &s, &c);
        apR[gid] = e * c;
        apI[gid] = e * s;
    } else if (gid < 2*TBL) {
        int gg = gid - TBL;
        int k = gg / DDIM, d = gg % DDIM;
        float g = -expf(log_gamma[d]);
        float w = omega[d];
        float ph = dta * (float)(16 * k);
        float e = expf(g * ph);
        float s, c;
        sincosf(w * ph, &s, &c);
        apgR[gg] = e * c;
        apgI[gg] = e * s;
    }
    if (gid < DDIM) {
        int d = band_idx[gid];              // gid = k*128 + j
        bandOf[d] = gid >> 7;
        posOf[d]  = gid & 127;
    }
}

// ---------------------------------------------------------------------------
// Kernel 2: FUSED gate + A-conversion. One wave per row m:
//  - gate[m] = sigmoid(x.Wg+bg) * (1 + tanh(sg)*mean|x-z|)
//  - Ahi/Alo[m][.] = bf16 hi/lo of x, PRE-SWIZZLED: src 16B-group gs of each
//    128B k-chunk lands at dst group gs^(m&7)  (matches GEMM ds_read XOR)
// ---------------------------------------------------------------------------
__global__ void k_cvtgate(const float* __restrict__ x,
                          const float* __restrict__ z_prev,
                          const float* __restrict__ Wg,
                          const float* __restrict__ bg,
                          const float* __restrict__ sg,
                          float* __restrict__ gate,
                          unsigned short* __restrict__ Ahi,
                          unsigned short* __restrict__ Alo)
{
    int m    = blockIdx.x * 4 + (threadIdx.x >> 6);
    int lane = threadIdx.x & 63;
    const float4* xr = (const float4*)(x      + ((size_t)m << 9));
    const float4* zr = (const float4*)(z_prev + ((size_t)m << 9));
    const float4* wg = (const float4*)Wg;
    float dot = 0.f, sur = 0.f;
    int msw = m & 7;
#pragma unroll
    for (int i = 0; i < 2; i++) {
        int e = lane + i*64;               // float4 index 0..127
        float4 a = xr[e];
        float4 z = zr[e];
        float4 w = wg[e];
        dot += a.x*w.x + a.y*w.y + a.z*w.z + a.w*w.w;
        sur += fabsf(a.x-z.x) + fabsf(a.y-z.y) + fabsf(a.z-z.z) + fabsf(a.w-z.w);
        // bf16 hi/lo split + swizzled store (4 elems = half a 16B group)
        float fa[4] = {a.x, a.y, a.z, a.w};
        u16x4 h, l;
#pragma unroll
        for (int j = 0; j < 4; ++j) {
            unsigned short hb = f2bf(fa[j]);
            h[j] = hb;
            l[j] = f2bf(fa[j] - bf2f(hb));
        }
        int grp = e >> 1, half = e & 1;
        int chunk = grp >> 3, gs = grp & 7;
        int gd = gs ^ msw;
        size_t dst = ((size_t)m << 9) + chunk*64 + gd*8 + half*4;
        *(u16x4*)(Ahi + dst) = h;
        *(u16x4*)(Alo + dst) = l;
    }
#pragma unroll
    for (int mm = 32; mm; mm >>= 1) { dot += __shfl_xor(dot, mm); sur += __shfl_xor(sur, mm); }
    if (lane == 0) {
        float g = 1.f / (1.f + expf(-(dot + bg[0])));
        g *= (1.f + tanhf(sg[0]) * (sur * (1.f/512.f)));
        gate[m] = g;
    }
}

// ---------------------------------------------------------------------------
// Kernel 3: convert W=[W_psi;W_phi] -> bf16 hi/lo planes, pre-swizzled by n&7
// ---------------------------------------------------------------------------
__global__ void k_cvtB(const float* __restrict__ Wpsi,
                       const float* __restrict__ Wphi,
                       unsigned short* __restrict__ Bhi,
                       unsigned short* __restrict__ Blo)
{
    int gid = blockIdx.x * 256 + threadIdx.x;   // NCOLS*64 threads
    int n = gid >> 6, grp = gid & 63;
    int chunk = grp >> 3, g = grp & 7;
    int se = chunk*64 + ((g ^ (n & 7)) << 3);
    const float* wp = (n < 1024) ? (Wpsi + ((size_t)n << 9) + se)
                                 : (Wphi + ((size_t)(n - 1024) << 9) + se);
    u16x8 h, l;
#pragma unroll
    for (int j = 0; j < 8; ++j) {
        float f = wp[j];
        unsigned short hb = f2bf(f);
        h[j] = hb;
        l[j] = f2bf(f - bf2f(hb));
    }
    size_t dst = ((size_t)n << 9) + grp*8;
    *(u16x8*)(Bhi + dst) = h;
    *(u16x8*)(Blo + dst) = l;
}

// ---------------------------------------------------------------------------
// Kernel 4: bf16 MFMA GEMM, 3-term split precision (UNCHANGED from round 2)
// ---------------------------------------------------------------------------
__global__ __launch_bounds__(256)
void k_gemm_bf16(const unsigned short* __restrict__ Ahi,
                 const unsigned short* __restrict__ Alo,
                 const unsigned short* __restrict__ Bhi,
                 const unsigned short* __restrict__ Blo,
                 const float* __restrict__ bpsi, const float* __restrict__ bphi,
                 float* __restrict__ psiR, float* __restrict__ psiI,
                 float* __restrict__ phiR, float* __restrict__ phiI)
{
    __shared__ __align__(16) char As[16384];
    __shared__ __align__(16) char Bs[16384];

    int bid = blockIdx.x;
    int wg  = (bid & 7) * 256 + (bid >> 3);   // XCD swizzle, nwg=2048 (%8==0)
    int m0 = (wg >> 4) * 128;
    int n0 = (wg & 15) * 128;

    int tid  = threadIdx.x;
    int lane = tid & 63;
    int wv   = tid >> 6;
    int wm = wv >> 1, wn = wv & 1;
    int lr = lane & 15, lk = lane >> 4;

    f32x4 acc[4][4];
#pragma unroll
    for (int mi = 0; mi < 4; ++mi)
#pragma unroll
        for (int ni = 0; ni < 4; ++ni) acc[mi][ni] = (f32x4)0.f;

    for (int s = 0; s < 24; ++s) {
        const unsigned short* Asrc = (s >= 8 && s < 16) ? Alo : Ahi;
        const unsigned short* Bsrc = (s < 16) ? Bhi : Blo;
        int kb2 = (s & 7) << 7;

        __syncthreads();
#pragma unroll
        for (int i = 0; i < 4; ++i) {
            int flat = tid + i * 256;
            int r = flat >> 3, g = flat & 7;
            size_t goff = ((size_t)r << 10) + kb2 + g * 16;
            gld_lds16((const char*)Asrc + ((size_t)m0 << 10) + goff,
                      As + (wv * 64 + i * 256) * 16);
            gld_lds16((const char*)Bsrc + ((size_t)n0 << 10) + goff,
                      Bs + (wv * 64 + i * 256) * 16);
        }
        __syncthreads();

#pragma unroll
        for (int kk = 0; kk < 2; ++kk) {
            int tb = (kk * 64 + lk * 16) ^ ((lr & 7) << 4);
            short8 af[4], bfr[4];
#pragma unroll
            for (int mi = 0; mi < 4; ++mi) {
                int r = wm * 64 + mi * 16 + lr;
                af[mi] = *(const short8*)(As + r * 128 + tb);
            }
#pragma unroll
            for (int ni = 0; ni < 4; ++ni) {
                int r = wn * 64 + ni * 16 + lr;
                bfr[ni] = *(const short8*)(Bs + r * 128 + tb);
            }
#pragma unroll
            for (int mi = 0; mi < 4; ++mi)
#pragma unroll
                for (int ni = 0; ni < 4; ++ni)
                    acc[mi][ni] = __builtin_amdgcn_mfma_f32_16x16x32_bf16(
                        af[mi], bfr[ni], acc[mi][ni], 0, 0, 0);
        }
    }

#pragma unroll
    for (int ni = 0; ni < 4; ++ni) {
        int ncol = n0 + wn * 64 + ni * 16 + lr;
        float bias = (ncol < 1024) ? bpsi[ncol] : bphi[ncol - 1024];
        int p = ncol >> 9;
        float* plane = (p == 0) ? psiR : (p == 1) ? psiI : (p == 2) ? phiR : phiI;
        int col = ncol & 511;
#pragma unroll
        for (int mi = 0; mi < 4; ++mi) {
            int mrow = m0 + wm * 64 + mi * 16 + lk * 4;
#pragma unroll
            for (int j = 0; j < 4; ++j)
                plane[(size_t)(mrow + j) * 512 + col] = acc[mi][ni][j] + bias;
        }
    }
}

// ---------------------------------------------------------------------------
// Kernel 5: chunked local scan (CHUNK=16), in place over psi planes.
// grid = BSZ*NCH = 1024 blocks (4/CU), 512 threads
// ---------------------------------------------------------------------------
__launch_bounds__(512)
__global__ void k_scan(float* __restrict__ HR, float* __restrict__ HI,
                       const float* __restrict__ gate,
                       const float* __restrict__ Bvec,
                       const float* __restrict__ apR, const float* __restrict__ apI,
                       float* __restrict__ carR, float* __restrict__ carI)
{
    int b = blockIdx.x >> 8;       // NCH = 256
    int c = blockIdx.x & 255;
    int d = threadIdx.x;
    float ar = apR[DDIM + d], ai = apI[DDIM + d];   // a^1
    float bv = Bvec[d];
    float hr = 0.f, hi = 0.f;
    int t0 = c * CHUNK;
    size_t base = ((size_t)b * LSEQ + t0) * DDIM + d;
    const float* grow = gate + (size_t)b * LSEQ + t0;
#pragma unroll
    for (int t = 0; t < CHUNK; t++) {
        float pr = HR[base], pi = HI[base];
        float g  = grow[t] * bv;
        float ur = g * pr, ui = g * pi;
        float nr = ar*hr - ai*hi + ur;
        float ni = ar*hi + ai*hr + ui;
        hr = nr; hi = ni;
        HR[base] = hr; HI[base] = hi;
        base += DDIM;
    }
    size_t ci = ((size_t)(b * NCH + c)) * DDIM + d;
    carR[ci] = hr; carI[ci] = hi;
}

// ---------------------------------------------------------------------------
// Kernel 6a: within-group (16 chunks) inclusive scan of chunk carries.
// 32768 threads: (b, cg, d), coalesced in d. q = a^CHUNK per d.
// ---------------------------------------------------------------------------
__global__ void k_carryA(float* __restrict__ carR, float* __restrict__ carI,
                         const float* __restrict__ apR, const float* __restrict__ apI)
{
    int gid = blockIdx.x * 256 + threadIdx.x;   // BSZ*NGRP*DDIM
    int d = gid & 511, cg = (gid >> 9) & 15, b = gid >> 13;
    float qr = apR[CHUNK*DDIM + d], qi = apI[CHUNK*DDIM + d];  // a^16
    size_t i0 = ((size_t)(b * NCH + cg * 16)) * DDIM + d;
    float cr = carR[i0], ci = carI[i0];
#pragma unroll
    for (int j = 1; j < 16; j++) {
        float xr = carR[i0 + (size_t)j * DDIM];
        float xi = carI[i0 + (size_t)j * DDIM];
        float nr = qr*cr - qi*ci + xr;
        float ni = qr*ci + qi*cr + xi;
        cr = nr; ci = ni;
        carR[i0 + (size_t)j * DDIM] = cr;
        carI[i0 + (size_t)j * DDIM] = ci;
    }
}

// ---------------------------------------------------------------------------
// Kernel 6b: combine group totals (15 steps, 2048 threads, Q = a^256)
// gcar[b][cg][d] = inclusive-across-groups total through group cg
// ---------------------------------------------------------------------------
__global__ void k_carryB(const float* __restrict__ carR, const float* __restrict__ carI,
                         const float* __restrict__ apgR, const float* __restrict__ apgI,
                         float* __restrict__ gcarR, float* __restrict__ gcarI)
{
    int gid = blockIdx.x * 256 + threadIdx.x;   // BSZ*DDIM = 2048
    int d = gid & 511, b = gid >> 9;
    float Qr = apgR[16*DDIM + d], Qi = apgI[16*DDIM + d];      // a^256
    size_t base = ((size_t)(b * NCH + 15)) * DDIM + d;         // last chunk of grp 0
    float gr = carR[base], gi = carI[base];
    gcarR[((size_t)(b*NGRP))*DDIM + d] = gr;
    gcarI[((size_t)(b*NGRP))*DDIM + d] = gi;
#pragma unroll
    for (int cg = 1; cg < NGRP; cg++) {
        size_t idx = ((size_t)(b * NCH + cg*16 + 15)) * DDIM + d;
        float tr = carR[idx], ti = carI[idx];
        float nr = Qr*gr - Qi*gi + tr;
        float ni = Qr*gi + Qi*gr + ti;
        gr = nr; gi = ni;
        gcarR[((size_t)(b*NGRP + cg))*DDIM + d] = gr;
        gcarI[((size_t)(b*NGRP + cg))*DDIM + d] = gi;
    }
}

// ---------------------------------------------------------------------------
// Kernel 6c: fixup — add prev-group inclusive total into every chunk carry
// car[c] += a^(16*((c&15)+1)) * gcar[cg-1],  for cg = c>>4 > 0
// ---------------------------------------------------------------------------
__global__ void k_carryC(float* __restrict__ carR, float* __restrict__ carI,
                         const float* __restrict__ apgR, const float* __restrict__ apgI,
                         const float* __restrict__ gcarR, const float* __restrict__ gcarI)
{
    int gid = blockIdx.x * 256 + threadIdx.x;   // BSZ*NCH*DDIM
    int d = gid & 511, c = (gid >> 9) & 255, b = gid >> 17;
    int cg = c >> 4;
    if (cg == 0) return;
    int jj = c & 15;
    float fr = apgR[(jj+1)*DDIM + d], fi = apgI[(jj+1)*DDIM + d];
    size_t gidx = ((size_t)(b*NGRP + cg - 1))*DDIM + d;
    float gr = gcarR[gidx], gi = gcarI[gidx];
    size_t idx = ((size_t)(b * NCH + c)) * DDIM + d;
    carR[idx] += fr*gr - fi*gi;
    carI[idx] += fr*gi + fi*gr;
}

// ---------------------------------------------------------------------------
// Kernel 7: carry fixup + exact projection + band mixing + output
// ---------------------------------------------------------------------------
__device__ __forceinline__ float2 blockSum2(float a, float b, float* red)
{
#pragma unroll
    for (int m = 32; m; m >>= 1) { a += __shfl_xor(a, m); b += __shfl_xor(b, m); }
    int tid = threadIdx.x, w = tid >> 6;
    if ((tid & 63) == 0) { red[w*2] = a; red[w*2+1] = b; }
    __syncthreads();
    a = 0.f; b = 0.f;
#pragma unroll
    for (int i = 0; i < 8; i++) { a += red[i*2]; b += red[i*2+1]; }
    __syncthreads();
    return make_float2(a, b);
}

__launch_bounds__(512)
__global__ void k_out(const float* __restrict__ HR, const float* __restrict__ HI,
                      const float* __restrict__ phR, const float* __restrict__ phI,
                      const float* __restrict__ carR, const float* __restrict__ carI,
                      const float* __restrict__ apR, const float* __restrict__ apI,
                      const int* __restrict__ bandOf, const int* __restrict__ posOf,
                      const float* __restrict__ tau, const float* __restrict__ beta,
                      float* __restrict__ out)
{
    __shared__ float sA[512], sB[512], sC[512];
    __shared__ float pA[8], pB[8], pC[8];
    __shared__ float red[16];

    int bt = blockIdx.x;
    int b = bt >> 12, t = bt & 4095;
    int d = threadIdx.x;
    size_t idx = (size_t)bt * DDIM + d;

    float hr = HR[idx], hi = HI[idx];
    int c = t >> 4, off = t & 15;               // CHUNK=16
    if (c > 0) {
        size_t ci = ((size_t)(b * NCH + (c - 1))) * DDIM + d;
        float cr = carR[ci], cm = carI[ci];
        float pr = apR[(off + 1) * DDIM + d], pi = apI[(off + 1) * DDIM + d];
        hr += pr*cr - pi*cm;
        hi += pr*cm + pi*cr;
    }
    float2 s = blockSum2(hr, hi, red);
    float mr = s.x * (1.f/512.f), mi = s.y * (1.f/512.f);
    float dr = hr - mr, di = hi - mi;
    float2 v = blockSum2(dr*dr, di*di, red);
    float Hpr = dr / (sqrtf(v.x * (1.f/512.f)) + 1e-6f);
    float Hpi = di / (sqrtf(v.y * (1.f/512.f)) + 1e-6f);

    float pr_ = phR[idx], pi_ = phI[idx];
    float ar_ = Hpr*pr_ + Hpi*pi_;     // conj(H)*phi  (real)
    float ai_ = Hpr*pi_ - Hpi*pr_;     // conj(H)*phi  (imag)
    float dn_ = Hpr*Hpr + Hpi*Hpi;

    int kb = bandOf[d], jb = posOf[d];
    sA[kb*128 + jb] = ar_;
    sB[kb*128 + jb] = ai_;
    sC[kb*128 + jb] = dn_;
    __syncthreads();

    float v0 = sA[d], v1 = sB[d], v2 = sC[d];
#pragma unroll
    for (int m = 32; m; m >>= 1) {
        v0 += __shfl_xor(v0, m); v1 += __shfl_xor(v1, m); v2 += __shfl_xor(v2, m);
    }
    int w = d >> 6;
    if ((d & 63) == 0) { pA[w] = v0; pB[w] = v1; pC[w] = v2; }
    __syncthreads();

    float tv = tau[0]; tv = (tv < 1e-4f) ? 1e-4f : tv;
    float bt_s = beta[0];
    float aRk[4], aIk[4], dnk[4], mag[4];
    float mx = -1e30f;
#pragma unroll
    for (int k = 0; k < 4; k++) {
        aRk[k] = (pA[2*k] + pA[2*k+1]) * (1.f/128.f);
        aIk[k] = (pB[2*k] + pB[2*k+1]) * (1.f/128.f);
        dnk[k] = (pC[2*k] + pC[2*k+1]) * (1.f/128.f);
        mag[k] = sqrtf(aRk[k]*aRk[k] + aIk[k]*aIk[k]) / tv;
        mx = fmaxf(mx, mag[k]);
    }
    float se = 0.f, ek[4];
#pragma unroll
    for (int k = 0; k < 4; k++) { ek[k] = expf(mag[k] - mx); se += ek[k]; }
    float inv = 1.f / se;

    int kd = kb;
    float ck  = ek[kd] * inv;
    float afR = aRk[kd] * ck * 4.f + bt_s * dnk[kd];
    float afI = aIk[kd] * ck * 4.f;
    out[idx] = Hpr * afR - Hpi * afI;
}

// ---------------------------------------------------------------------------
extern "C" void kernel_launch(void* const* d_in, const int* in_sizes, int n_in,
                              void* d_out, int out_size, void* d_ws, size_t ws_size,
                              hipStream_t stream)
{
    const float* x        = (const float*)d_in[0];
    const float* z_prev   = (const float*)d_in[1];
    const float* W_psi    = (const float*)d_in[2];
    const float* b_psi    = (const float*)d_in[3];
    const float* W_phi    = (const float*)d_in[4];
    const float* b_phi    = (const float*)d_in[5];
    const float* W_gate   = (const float*)d_in[6];
    const float* b_gate   = (const float*)d_in[7];
    const float* omega    = (const float*)d_in[8];
    const float* log_gam  = (const float*)d_in[9];
    const float* dt       = (const float*)d_in[10];
    const float* sg       = (const float*)d_in[11];
    const float* tau      = (const float*)d_in[12];
    const float* beta     = (const float*)d_in[13];
    const float* B_vec    = (const float*)d_in[14];
    const int*   band_idx = (const int*)d_in[15];
    float* out = (float*)d_out;
    float* ws  = (float*)d_ws;

    // workspace layout (floats)
    float* psiR = ws;                    // BLD  -> becomes H_re after scan
    float* psiI = psiR + BLD;            // BLD  -> becomes H_im
    float* phiR = psiI + BLD;            // BLD
    float* phiI = phiR + BLD;            // BLD
    float* gate = phiI + BLD;            // MROWS
    float* apR  = gate + MROWS;          // TBL
    float* apI  = apR + TBL;             // TBL
    float* apgR = apI + TBL;             // TBL
    float* apgI = apgR + TBL;            // TBL
    float* carR = apgI + TBL;            // BSZ*NCH*DDIM
    float* carI = carR + (size_t)BSZ*NCH*DDIM;
    float* gcarR = carI + (size_t)BSZ*NCH*DDIM;   // BSZ*NGRP*DDIM
    float* gcarI = gcarR + (size_t)BSZ*NGRP*DDIM;
    int* bandOf = (int*)(gcarI + (size_t)BSZ*NGRP*DDIM);  // DDIM
    int* posOf  = bandOf + DDIM;                          // DDIM
    unsigned short* Bhi = (unsigned short*)(posOf + DDIM);   // NCOLS*512 bf16
    unsigned short* Blo = Bhi + (size_t)NCOLS*512;           // NCOLS*512 bf16

    // A-operand bf16 planes live in d_out (dead until k_out writes it)
    unsigned short* Ahi = (unsigned short*)d_out;
    unsigned short* Alo = Ahi + (size_t)MROWS*512;

    k_prep<<<(2*TBL + 255)/256, 256, 0, stream>>>(
        omega, log_gam, dt, band_idx, apR, apI, apgR, apgI, bandOf, posOf);

    k_cvtgate<<<MROWS/4, 256, 0, stream>>>(x, z_prev, W_gate, b_gate, sg,
                                           gate, Ahi, Alo);

    k_cvtB<<<(NCOLS*64)/256, 256, 0, stream>>>(W_psi, W_phi, Bhi, Blo);

    k_gemm_bf16<<<(MROWS/128) * (NCOLS/128), 256, 0, stream>>>(
        Ahi, Alo, Bhi, Blo, b_psi, b_phi, psiR, psiI, phiR, phiI);

    k_scan<<<BSZ * NCH, 512, 0, stream>>>(psiR, psiI, gate, B_vec, apR, apI, carR, carI);

    k_carryA<<<(BSZ*NGRP*DDIM)/256, 256, 0, stream>>>(carR, carI, apR, apI);
    k_carryB<<<(BSZ*DDIM)/256, 256, 0, stream>>>(carR, carI, apgR, apgI, gcarR, gcarI);
    k_carryC<<<(BSZ*NCH*DDIM)/256, 256, 0, stream>>>(carR, carI, apgR, apgI, gcarR, gcarI);

    k_out<<<MROWS, 512, 0, stream>>>(psiR, psiI, phiR, phiI, carR, carI,
                                     apR, apI, bandOf, posOf, tau, beta, out);
}